// Round 1
// baseline (271.439 us; speedup 1.0000x reference)
//
#include <hip/hip_runtime.h>

typedef __bf16 bf16x8 __attribute__((ext_vector_type(8)));
typedef float f32x4 __attribute__((ext_vector_type(4)));

#define LOG2E 1.4426950408889634f

static __device__ __forceinline__ unsigned short f2bf(float f){
  unsigned int u = __builtin_bit_cast(unsigned int, f);
  u += 0x7FFFu + ((u >> 16) & 1u);
  return (unsigned short)(u >> 16);
}

// ---------------- kernel 0: weights -> transposed bf16 [384][1024] ----------------
__global__ __launch_bounds__(256) void k_prepw(const float* __restrict__ Wq,
                                               const float* __restrict__ Wk,
                                               const float* __restrict__ Wv,
                                               unsigned short* __restrict__ Wtb){
  int idx = blockIdx.x * 256 + threadIdx.x;   // 0 .. 384*1024-1
  int m = idx >> 10;                           // output row (0..383)
  int k = idx & 1023;                          // contraction index
  const float* W = (m < 128) ? Wq : ((m < 256) ? Wk : Wv);
  int n = m & 127;
  Wtb[idx] = f2bf(W[k * 128 + n]);
}

// ---------------- kernel 1: O[16384][384] = x @ [Wq|Wk|Wv]  (bf16 MFMA) ----------------
__global__ __launch_bounds__(256) void k_gemm(const float* __restrict__ x,
                                              const unsigned short* __restrict__ Wtb,
                                              float* __restrict__ O){
  __shared__ __align__(16) unsigned short sA[128][40];  // 80B rows: conflict-light
  __shared__ __align__(16) unsigned short sB[128][40];

  int bid  = blockIdx.x;          // 384 blocks
  int mblk = bid & 127;
  int nblk = bid >> 7;            // 0..2
  int tid  = threadIdx.x;
  int wid  = tid >> 6, lane = tid & 63;
  int wm = wid >> 1, wn = wid & 1;
  int g = lane >> 4, lr = lane & 15;

  f32x4 acc[4][4] = {};

  const float* xbase = x + (size_t)(mblk * 128) * 1024;
  const unsigned short* wbase = Wtb + (size_t)(nblk * 128) * 1024;

  for (int k0 = 0; k0 < 1024; k0 += 32){
    __syncthreads();
    // stage A: 128x32 fp32 -> bf16, coalesced float4 reads
#pragma unroll
    for (int p = 0; p < 4; p++){
      int idx = tid + p * 256;             // 0..1023
      int r = idx >> 3, c4 = (idx & 7) * 4;
      float4 v = *reinterpret_cast<const float4*>(xbase + (size_t)r * 1024 + k0 + c4);
      uint2 pk;
      pk.x = ((unsigned int)f2bf(v.y) << 16) | f2bf(v.x);
      pk.y = ((unsigned int)f2bf(v.w) << 16) | f2bf(v.z);
      *reinterpret_cast<uint2*>(&sA[r][c4]) = pk;
    }
    // stage B: 128x32 bf16 (already K-major), 16B copies
#pragma unroll
    for (int p = 0; p < 2; p++){
      int idx = tid + p * 256;             // 0..511
      int r = idx >> 2, c8 = (idx & 3) * 8;
      *reinterpret_cast<uint4*>(&sB[r][c8]) =
        *reinterpret_cast<const uint4*>(wbase + (size_t)r * 1024 + k0 + c8);
    }
    __syncthreads();

    bf16x8 af[4], bfg[4];
#pragma unroll
    for (int m = 0; m < 4; m++)
      af[m] = *reinterpret_cast<const bf16x8*>(&sA[wm * 64 + m * 16 + lr][g * 8]);
#pragma unroll
    for (int n = 0; n < 4; n++)
      bfg[n] = *reinterpret_cast<const bf16x8*>(&sB[wn * 64 + n * 16 + lr][g * 8]);
#pragma unroll
    for (int m = 0; m < 4; m++)
#pragma unroll
      for (int n = 0; n < 4; n++)
        acc[m][n] = __builtin_amdgcn_mfma_f32_16x16x32_bf16(af[m], bfg[n], acc[m][n], 0, 0, 0);
  }

#pragma unroll
  for (int m = 0; m < 4; m++)
#pragma unroll
    for (int n = 0; n < 4; n++)
#pragma unroll
      for (int r = 0; r < 4; r++){
        int row = mblk * 128 + wm * 64 + m * 16 + g * 4 + r;
        int col = nblk * 128 + wn * 64 + n * 16 + lr;
        O[(size_t)row * 384 + col] = acc[m][n][r];
      }
}

// ---------------- kernel 2: RoPE on q,k; writes bf16 Qr (pre-scaled), Kr ----------------
__global__ __launch_bounds__(256) void k_rope(const float* __restrict__ O,
                                              unsigned int* __restrict__ Qr,
                                              unsigned int* __restrict__ Kr){
  int idx = blockIdx.x * 256 + threadIdx.x;   // 0 .. 16384*64-1
  int row = idx >> 6;                          // b*2048 + t
  int i = idx & 63;
  int t = row & 2047;
  // theta_i = 10000^((2-2i)/64)
  float theta = exp2f(13.287712379549449f * (2.0f - 2.0f * (float)i) * 0.015625f);
  float ang = (float)t * theta;
  float s, c;
  sincosf(ang, &s, &c);
  const float* p = O + (size_t)row * 384;
  float2 q2 = *reinterpret_cast<const float2*>(p + 2 * i);
  float2 k2 = *reinterpret_cast<const float2*>(p + 128 + 2 * i);
  const float scale = 0.08838834764831845f;    // 128^-0.5 folded into Q
  float qe = (q2.x * c + q2.y * s) * scale;
  float qo = (-q2.x * s + q2.y * c) * scale;
  float ke = k2.x * c + k2.y * s;
  float ko = -k2.x * s + k2.y * c;
  Qr[row * 64 + i] = ((unsigned int)f2bf(qo) << 16) | f2bf(qe);
  Kr[row * 64 + i] = ((unsigned int)f2bf(ko) << 16) | f2bf(ke);
}

// ---------------- kernel 3: V -> Vt[b][h][t] bf16 (tiled transpose) ----------------
__global__ __launch_bounds__(256) void k_vt(const float* __restrict__ O,
                                            unsigned short* __restrict__ Vt){
  __shared__ unsigned short sT[64][132];
  int b = blockIdx.x >> 5, tc = blockIdx.x & 31;
  int t0 = tc * 64;
  int tid = threadIdx.x;
#pragma unroll
  for (int p = 0; p < 8; p++){
    int idx = tid + p * 256;                 // 0..2047
    int tl = idx >> 5, h0 = (idx & 31) * 4;
    float4 v = *reinterpret_cast<const float4*>(
        O + ((size_t)(b * 2048 + t0 + tl)) * 384 + 256 + h0);
    uint2 pk;
    pk.x = ((unsigned int)f2bf(v.y) << 16) | f2bf(v.x);
    pk.y = ((unsigned int)f2bf(v.w) << 16) | f2bf(v.z);
    *reinterpret_cast<uint2*>(&sT[tl][h0]) = pk;
  }
  __syncthreads();
#pragma unroll
  for (int p = 0; p < 8; p++){
    int q = tid + p * 256;                   // 0..2047
    int h = q >> 4, tl0 = (q & 15) * 4;
    ushort4 o;
    o.x = sT[tl0 + 0][h];
    o.y = sT[tl0 + 1][h];
    o.z = sT[tl0 + 2][h];
    o.w = sT[tl0 + 3][h];
    *reinterpret_cast<ushort4*>(Vt + ((size_t)(b * 128 + h)) * 2048 + t0 + tl0) = o;
  }
}

// ---------------- kernel 4: causal flash attention ----------------
__global__ __launch_bounds__(128) void k_attn(const unsigned short* __restrict__ Qr,
                                              const unsigned short* __restrict__ Kr,
                                              const unsigned short* __restrict__ Vt,
                                              float* __restrict__ out){
  __shared__ __align__(16) unsigned short sK[32][136];   // [kv][h]
  __shared__ __align__(16) unsigned short sV[128][40];   // [h][kv]
  __shared__ __align__(16) unsigned short sP[2][16][40]; // per-wave [qrow][kv]

  int b = blockIdx.x >> 6, qt = blockIdx.x & 63;
  int q_base = qt * 32;
  int tid = threadIdx.x, w = tid >> 6, lane = tid & 63;
  int g = lane >> 4, lr = lane & 15;

  // Q fragments in registers (row = lr within wave's 16 rows)
  int qrow = q_base + w * 16 + lr;
  const unsigned short* qptr = Qr + ((size_t)(b * 2048 + qrow)) * 128;
  bf16x8 qf[4];
#pragma unroll
  for (int hc = 0; hc < 4; hc++)
    qf[hc] = *reinterpret_cast<const bf16x8*>(qptr + hc * 32 + g * 8);

  f32x4 oacc[8] = {};
  float mrow[4], lrow[4];
#pragma unroll
  for (int r = 0; r < 4; r++){ mrow[r] = -1e30f; lrow[r] = 0.0f; }

  const unsigned short* Kb = Kr + (size_t)b * 2048 * 128;
  const unsigned short* Vb = Vt + (size_t)b * 128 * 2048;
  int niter = qt + 1;

  for (int it = 0; it < niter; it++){
    int kv0 = it * 32;
    __syncthreads();
    // stage K tile [32][128]
#pragma unroll
    for (int p = 0; p < 4; p++){
      int idx = tid + p * 128;               // 0..511
      int r = idx >> 4, c8 = (idx & 15) * 8;
      *reinterpret_cast<uint4*>(&sK[r][c8]) =
        *reinterpret_cast<const uint4*>(Kb + (size_t)(kv0 + r) * 128 + c8);
    }
    // stage V^T tile [128][32]
#pragma unroll
    for (int p = 0; p < 4; p++){
      int idx = tid + p * 128;               // 0..511
      int h = idx >> 2, c8 = (idx & 3) * 8;
      *reinterpret_cast<uint4*>(&sV[h][c8]) =
        *reinterpret_cast<const uint4*>(Vb + (size_t)h * 2048 + kv0 + c8);
    }
    __syncthreads();

    // QK^T: per wave S[16 q][32 kv], 2 col tiles
    f32x4 sacc[2] = {};
#pragma unroll
    for (int ct = 0; ct < 2; ct++){
      f32x4 a = {0.f, 0.f, 0.f, 0.f};
#pragma unroll
      for (int hc = 0; hc < 4; hc++){
        bf16x8 kf = *reinterpret_cast<const bf16x8*>(&sK[ct * 16 + lr][hc * 32 + g * 8]);
        a = __builtin_amdgcn_mfma_f32_16x16x32_bf16(qf[hc], kf, a, 0, 0, 0);
      }
      sacc[ct] = a;
    }

    bool lastt = (it == qt);
    float alpha[4];
#pragma unroll
    for (int r = 0; r < 4; r++){
      float s0 = sacc[0][r], s1 = sacc[1][r];
      if (lastt){
        int row = q_base + w * 16 + g * 4 + r;
        if (kv0 + lr      > row) s0 = -1e30f;
        if (kv0 + 16 + lr > row) s1 = -1e30f;
      }
      float mx = fmaxf(s0, s1);
      mx = fmaxf(mx, __shfl_xor(mx, 1));
      mx = fmaxf(mx, __shfl_xor(mx, 2));
      mx = fmaxf(mx, __shfl_xor(mx, 4));
      mx = fmaxf(mx, __shfl_xor(mx, 8));
      float m = fmaxf(mrow[r], mx);
      float p0 = exp2f((s0 - m) * LOG2E);
      float p1 = exp2f((s1 - m) * LOG2E);
      float rs = p0 + p1;
      rs += __shfl_xor(rs, 1);
      rs += __shfl_xor(rs, 2);
      rs += __shfl_xor(rs, 4);
      rs += __shfl_xor(rs, 8);
      alpha[r] = exp2f((mrow[r] - m) * LOG2E);
      lrow[r] = lrow[r] * alpha[r] + rs;
      mrow[r] = m;
      sP[w][g * 4 + r][lr]      = f2bf(p0);
      sP[w][g * 4 + r][16 + lr] = f2bf(p1);
    }
    // rescale O accumulator
#pragma unroll
    for (int ht = 0; ht < 8; ht++)
#pragma unroll
      for (int r = 0; r < 4; r++)
        oacc[ht][r] *= alpha[r];

    __syncthreads();   // make sP visible (and order vs next staging)

    // PV: O[16 q][128 h] += P[16][32] @ V[32][128]
    bf16x8 pa = *reinterpret_cast<const bf16x8*>(&sP[w][lr][g * 8]);
#pragma unroll
    for (int ht = 0; ht < 8; ht++){
      bf16x8 vf = *reinterpret_cast<const bf16x8*>(&sV[ht * 16 + lr][g * 8]);
      oacc[ht] = __builtin_amdgcn_mfma_f32_16x16x32_bf16(pa, vf, oacc[ht], 0, 0, 0);
    }
  }

  // epilogue: divide by l, store fp32
  float inv[4];
#pragma unroll
  for (int r = 0; r < 4; r++) inv[r] = 1.0f / lrow[r];
#pragma unroll
  for (int ht = 0; ht < 8; ht++)
#pragma unroll
    for (int r = 0; r < 4; r++){
      int row = q_base + w * 16 + g * 4 + r;
      int col = ht * 16 + lr;
      out[((size_t)(b * 2048 + row)) * 128 + col] = oacc[ht][r] * inv[r];
    }
}

extern "C" void kernel_launch(void* const* d_in, const int* in_sizes, int n_in,
                              void* d_out, int out_size, void* d_ws, size_t ws_size,
                              hipStream_t stream) {
  const float* x  = (const float*)d_in[0];
  const float* Wq = (const float*)d_in[1];
  const float* Wk = (const float*)d_in[2];
  const float* Wv = (const float*)d_in[3];
  float* out = (float*)d_out;

  char* ws = (char*)d_ws;
  unsigned short* Wtb = (unsigned short*)ws;                       // 786,432 B
  float* O            = (float*)(ws + 786432);                     // 25,165,824 B
  unsigned int* Qr    = (unsigned int*)(ws + 786432 + 25165824);   // 4,194,304 B
  unsigned int* Kr    = (unsigned int*)(ws + 786432 + 25165824 + 4194304);
  unsigned short* Vt  = (unsigned short*)(ws + 786432 + 25165824 + 2 * 4194304);

  hipLaunchKernelGGL(k_prepw, dim3(1536), dim3(256), 0, stream, Wq, Wk, Wv, Wtb);
  hipLaunchKernelGGL(k_gemm,  dim3(384),  dim3(256), 0, stream, x, Wtb, O);
  hipLaunchKernelGGL(k_rope,  dim3(4096), dim3(256), 0, stream, O, Qr, Kr);
  hipLaunchKernelGGL(k_vt,    dim3(256),  dim3(256), 0, stream, O, Vt);
  hipLaunchKernelGGL(k_attn,  dim3(512),  dim3(128), 0, stream,
                     (const unsigned short*)Qr, (const unsigned short*)Kr, Vt, out);
}

// Round 2
// 110.768 us; speedup vs baseline: 2.4505x; 2.4505x over previous
//
#include <hip/hip_runtime.h>

typedef __bf16 bf16x8 __attribute__((ext_vector_type(8)));
typedef float f32x4 __attribute__((ext_vector_type(4)));

#define LOG2E 1.4426950408889634f

static __device__ __forceinline__ unsigned short f2bf(float f){
  unsigned int u = __builtin_bit_cast(unsigned int, f);
  u += 0x7FFFu + ((u >> 16) & 1u);
  return (unsigned short)(u >> 16);
}
static __device__ __forceinline__ float bf2f(unsigned short h){
  unsigned int u = ((unsigned int)h) << 16;
  return __builtin_bit_cast(float, u);
}

// ---------------- kernel 0: weights -> transposed bf16 [384][1024] ----------------
__global__ __launch_bounds__(256) void k_prepw(const float* __restrict__ Wq,
                                               const float* __restrict__ Wk,
                                               const float* __restrict__ Wv,
                                               unsigned short* __restrict__ Wtb){
  int idx = blockIdx.x * 256 + threadIdx.x;   // 0 .. 384*1024-1
  int m = idx >> 10;                           // output row (0..383)
  int k = idx & 1023;                          // contraction index
  const float* W = (m < 128) ? Wq : ((m < 256) ? Wk : Wv);
  int n = m & 127;
  Wtb[idx] = f2bf(W[k * 128 + n]);
}

// ---------------- kernel 1: O[16384][384] = x @ [Wq|Wk|Wv]  (bf16 MFMA) ----------------
__global__ __launch_bounds__(256) void k_gemm(const float* __restrict__ x,
                                              const unsigned short* __restrict__ Wtb,
                                              float* __restrict__ O){
  __shared__ __align__(16) unsigned short sA[128][40];
  __shared__ __align__(16) unsigned short sB[128][40];

  int bid  = blockIdx.x;          // 384 blocks
  int mblk = bid & 127;
  int nblk = bid >> 7;            // 0..2
  int tid  = threadIdx.x;
  int wid  = tid >> 6, lane = tid & 63;
  int wm = wid >> 1, wn = wid & 1;
  int g = lane >> 4, lr = lane & 15;

  f32x4 acc[4][4] = {};

  const float* xbase = x + (size_t)(mblk * 128) * 1024;
  const unsigned short* wbase = Wtb + (size_t)(nblk * 128) * 1024;

  for (int k0 = 0; k0 < 1024; k0 += 32){
    __syncthreads();
#pragma unroll
    for (int p = 0; p < 4; p++){
      int idx = tid + p * 256;             // 0..1023
      int r = idx >> 3, c4 = (idx & 7) * 4;
      float4 v = *reinterpret_cast<const float4*>(xbase + (size_t)r * 1024 + k0 + c4);
      uint2 pk;
      pk.x = ((unsigned int)f2bf(v.y) << 16) | f2bf(v.x);
      pk.y = ((unsigned int)f2bf(v.w) << 16) | f2bf(v.z);
      *reinterpret_cast<uint2*>(&sA[r][c4]) = pk;
    }
#pragma unroll
    for (int p = 0; p < 2; p++){
      int idx = tid + p * 256;             // 0..511
      int r = idx >> 2, c8 = (idx & 3) * 8;
      *reinterpret_cast<uint4*>(&sB[r][c8]) =
        *reinterpret_cast<const uint4*>(wbase + (size_t)r * 1024 + k0 + c8);
    }
    __syncthreads();

    bf16x8 af[4], bfg[4];
#pragma unroll
    for (int m = 0; m < 4; m++)
      af[m] = *reinterpret_cast<const bf16x8*>(&sA[wm * 64 + m * 16 + lr][g * 8]);
#pragma unroll
    for (int n = 0; n < 4; n++)
      bfg[n] = *reinterpret_cast<const bf16x8*>(&sB[wn * 64 + n * 16 + lr][g * 8]);
#pragma unroll
    for (int m = 0; m < 4; m++)
#pragma unroll
      for (int n = 0; n < 4; n++)
        acc[m][n] = __builtin_amdgcn_mfma_f32_16x16x32_bf16(af[m], bfg[n], acc[m][n], 0, 0, 0);
  }

#pragma unroll
  for (int m = 0; m < 4; m++)
#pragma unroll
    for (int n = 0; n < 4; n++)
#pragma unroll
      for (int r = 0; r < 4; r++){
        int row = mblk * 128 + wm * 64 + m * 16 + g * 4 + r;
        int col = nblk * 128 + wn * 64 + n * 16 + lr;
        O[(size_t)row * 384 + col] = acc[m][n][r];
      }
}

// ---------------- kernel 2: RoPE on q,k; writes bf16 Qr (pre-scaled), Kr ----------------
__global__ __launch_bounds__(256) void k_rope(const float* __restrict__ O,
                                              unsigned int* __restrict__ Qr,
                                              unsigned int* __restrict__ Kr){
  int idx = blockIdx.x * 256 + threadIdx.x;   // 0 .. 16384*64-1
  int row = idx >> 6;                          // b*2048 + t
  int i = idx & 63;
  int t = row & 2047;
  float theta = exp2f(13.287712379549449f * (2.0f - 2.0f * (float)i) * 0.015625f);
  float ang = (float)t * theta;
  float s, c;
  sincosf(ang, &s, &c);
  const float* p = O + (size_t)row * 384;
  float2 q2 = *reinterpret_cast<const float2*>(p + 2 * i);
  float2 k2 = *reinterpret_cast<const float2*>(p + 128 + 2 * i);
  const float scale = 0.08838834764831845f;    // 128^-0.5 folded into Q
  float qe = (q2.x * c + q2.y * s) * scale;
  float qo = (-q2.x * s + q2.y * c) * scale;
  float ke = k2.x * c + k2.y * s;
  float ko = -k2.x * s + k2.y * c;
  Qr[row * 64 + i] = ((unsigned int)f2bf(qo) << 16) | f2bf(qe);
  Kr[row * 64 + i] = ((unsigned int)f2bf(ko) << 16) | f2bf(ke);
}

// ---------------- kernel 3: V -> Vt[b][h][t] bf16 (tiled transpose) ----------------
__global__ __launch_bounds__(256) void k_vt(const float* __restrict__ O,
                                            unsigned short* __restrict__ Vt){
  __shared__ unsigned short sT[64][132];
  int b = blockIdx.x >> 5, tc = blockIdx.x & 31;
  int t0 = tc * 64;
  int tid = threadIdx.x;
#pragma unroll
  for (int p = 0; p < 8; p++){
    int idx = tid + p * 256;                 // 0..2047
    int tl = idx >> 5, h0 = (idx & 31) * 4;
    float4 v = *reinterpret_cast<const float4*>(
        O + ((size_t)(b * 2048 + t0 + tl)) * 384 + 256 + h0);
    uint2 pk;
    pk.x = ((unsigned int)f2bf(v.y) << 16) | f2bf(v.x);
    pk.y = ((unsigned int)f2bf(v.w) << 16) | f2bf(v.z);
    *reinterpret_cast<uint2*>(&sT[tl][h0]) = pk;
  }
  __syncthreads();
#pragma unroll
  for (int p = 0; p < 8; p++){
    int q = tid + p * 256;                   // 0..2047
    int h = q >> 4, tl0 = (q & 15) * 4;
    ushort4 o;
    o.x = sT[tl0 + 0][h];
    o.y = sT[tl0 + 1][h];
    o.z = sT[tl0 + 2][h];
    o.w = sT[tl0 + 3][h];
    *reinterpret_cast<ushort4*>(Vt + ((size_t)(b * 128 + h)) * 2048 + t0 + tl0) = o;
  }
}

// ---------------- kernel 4: causal flash attention, split-KV partials ----------------
// Each block: one (b, q-tile of 32 rows, KV chunk of <=512). Writes unnormalized
// O partial (bf16) + per-row running max m and sum l (fp32).
__global__ __launch_bounds__(128) void k_attn_part(const unsigned short* __restrict__ Qr,
                                                   const unsigned short* __restrict__ Kr,
                                                   const unsigned short* __restrict__ Vt,
                                                   unsigned short* __restrict__ Opart,
                                                   float* __restrict__ ml){
  __shared__ __align__(16) unsigned short sK[32][136];   // [kv][h]
  __shared__ __align__(16) unsigned short sV[128][40];   // [h][kv]
  __shared__ __align__(16) unsigned short sP[2][16][40]; // per-wave [qrow][kv]

  int bid = blockIdx.x;
  int b = bid / 160;
  int rem = bid - b * 160;
  int qt, c;
  if (rem < 16)      { qt = rem;                    c = 0; }
  else if (rem < 48) { qt = 16 + ((rem - 16) >> 1); c = (rem - 16) & 1; }
  else if (rem < 96) { int r2 = rem - 48; int d = r2 / 3; qt = 32 + d; c = r2 - 3 * d; }
  else               { int r3 = rem - 96; qt = 48 + (r3 >> 2); c = r3 & 3; }

  int q_base = qt * 32;
  int kv_start = c * 512;
  int kv_end = min(kv_start + 512, q_base + 32);
  int niter = (kv_end - kv_start) >> 5;

  int tid = threadIdx.x, w = tid >> 6, lane = tid & 63;
  int g = lane >> 4, lr = lane & 15;

  int qrow = q_base + w * 16 + lr;
  const unsigned short* qptr = Qr + ((size_t)(b * 2048 + qrow)) * 128;
  bf16x8 qf[4];
#pragma unroll
  for (int hc = 0; hc < 4; hc++)
    qf[hc] = *reinterpret_cast<const bf16x8*>(qptr + hc * 32 + g * 8);

  f32x4 oacc[8] = {};
  float mrow[4], lrow[4];
#pragma unroll
  for (int r = 0; r < 4; r++){ mrow[r] = -1e30f; lrow[r] = 0.0f; }

  const unsigned short* Kb = Kr + (size_t)b * 2048 * 128;
  const unsigned short* Vb = Vt + (size_t)b * 128 * 2048;

  for (int it = 0; it < niter; it++){
    int kv0 = kv_start + it * 32;
    __syncthreads();
#pragma unroll
    for (int p = 0; p < 4; p++){
      int idx = tid + p * 128;               // 0..511
      int r = idx >> 4, c8 = (idx & 15) * 8;
      *reinterpret_cast<uint4*>(&sK[r][c8]) =
        *reinterpret_cast<const uint4*>(Kb + (size_t)(kv0 + r) * 128 + c8);
    }
#pragma unroll
    for (int p = 0; p < 4; p++){
      int idx = tid + p * 128;               // 0..511
      int h = idx >> 2, c8 = (idx & 3) * 8;
      *reinterpret_cast<uint4*>(&sV[h][c8]) =
        *reinterpret_cast<const uint4*>(Vb + (size_t)h * 2048 + kv0 + c8);
    }
    __syncthreads();

    f32x4 sacc[2] = {};
#pragma unroll
    for (int ct = 0; ct < 2; ct++){
      f32x4 a = {0.f, 0.f, 0.f, 0.f};
#pragma unroll
      for (int hc = 0; hc < 4; hc++){
        bf16x8 kf = *reinterpret_cast<const bf16x8*>(&sK[ct * 16 + lr][hc * 32 + g * 8]);
        a = __builtin_amdgcn_mfma_f32_16x16x32_bf16(qf[hc], kf, a, 0, 0, 0);
      }
      sacc[ct] = a;
    }

    float alpha[4];
#pragma unroll
    for (int r = 0; r < 4; r++){
      float s0 = sacc[0][r], s1 = sacc[1][r];
      int row = q_base + w * 16 + g * 4 + r;
      if (kv0 + lr      > row) s0 = -1e30f;
      if (kv0 + 16 + lr > row) s1 = -1e30f;
      float mx = fmaxf(s0, s1);
      mx = fmaxf(mx, __shfl_xor(mx, 1));
      mx = fmaxf(mx, __shfl_xor(mx, 2));
      mx = fmaxf(mx, __shfl_xor(mx, 4));
      mx = fmaxf(mx, __shfl_xor(mx, 8));
      float m = fmaxf(mrow[r], mx);
      float p0 = exp2f((s0 - m) * LOG2E);
      float p1 = exp2f((s1 - m) * LOG2E);
      float rs = p0 + p1;
      rs += __shfl_xor(rs, 1);
      rs += __shfl_xor(rs, 2);
      rs += __shfl_xor(rs, 4);
      rs += __shfl_xor(rs, 8);
      alpha[r] = exp2f((mrow[r] - m) * LOG2E);
      lrow[r] = lrow[r] * alpha[r] + rs;
      mrow[r] = m;
      sP[w][g * 4 + r][lr]      = f2bf(p0);
      sP[w][g * 4 + r][16 + lr] = f2bf(p1);
    }
#pragma unroll
    for (int ht = 0; ht < 8; ht++)
#pragma unroll
      for (int r = 0; r < 4; r++)
        oacc[ht][r] *= alpha[r];

    // sP is written and read by the SAME wave -> no barrier needed here.
    bf16x8 pa = *reinterpret_cast<const bf16x8*>(&sP[w][lr][g * 8]);
#pragma unroll
    for (int ht = 0; ht < 8; ht++){
      bf16x8 vf = *reinterpret_cast<const bf16x8*>(&sV[ht * 16 + lr][g * 8]);
      oacc[ht] = __builtin_amdgcn_mfma_f32_16x16x32_bf16(pa, vf, oacc[ht], 0, 0, 0);
    }
  }

  // write partial: unnormalized bf16 O + (m,l)
  size_t slot = (size_t)(b * 64 + qt) * 4 + c;
  unsigned short* op = Opart + slot * 4096;
  float* mlp = ml + slot * 64;
#pragma unroll
  for (int ht = 0; ht < 8; ht++)
#pragma unroll
    for (int r = 0; r < 4; r++){
      int rowl = w * 16 + g * 4 + r;
      op[rowl * 128 + ht * 16 + lr] = f2bf(oacc[ht][r]);
    }
  if (lr == 0){
#pragma unroll
    for (int r = 0; r < 4; r++){
      int rowl = w * 16 + g * 4 + r;
      mlp[rowl]      = mrow[r];
      mlp[32 + rowl] = lrow[r];
    }
  }
}

// ---------------- kernel 5: combine partials ----------------
__global__ __launch_bounds__(256) void k_comb(const unsigned short* __restrict__ Opart,
                                              const float* __restrict__ ml,
                                              float* __restrict__ out){
  int bid = blockIdx.x;          // 512 = 8 b * 64 qt
  int b = bid >> 6, qt = bid & 63;
  int nck = (qt >> 4) + 1;
  int tid = threadIdx.x;
  int row = tid >> 3;            // 0..31
  int col0 = (tid & 7) * 16;
  size_t slot0 = (size_t)(b * 64 + qt) * 4;

  float m_c[4], l_c[4];
  float M = -1e30f;
#pragma unroll
  for (int c = 0; c < 4; c++) if (c < nck){
    m_c[c] = ml[(slot0 + c) * 64 + row];
    l_c[c] = ml[(slot0 + c) * 64 + 32 + row];
    M = fmaxf(M, m_c[c]);
  }
  float L = 0.0f, wgt[4];
#pragma unroll
  for (int c = 0; c < 4; c++) if (c < nck){
    wgt[c] = exp2f((m_c[c] - M) * LOG2E);
    L += wgt[c] * l_c[c];
  }
  float acc[16] = {};
#pragma unroll
  for (int c = 0; c < 4; c++) if (c < nck){
    const unsigned short* src = Opart + (slot0 + c) * 4096 + row * 128 + col0;
    uint4 u0 = *reinterpret_cast<const uint4*>(src);
    uint4 u1 = *reinterpret_cast<const uint4*>(src + 8);
    unsigned int uu[8] = {u0.x, u0.y, u0.z, u0.w, u1.x, u1.y, u1.z, u1.w};
#pragma unroll
    for (int j = 0; j < 8; j++){
      acc[2 * j]     += wgt[c] * bf2f((unsigned short)(uu[j] & 0xFFFF));
      acc[2 * j + 1] += wgt[c] * bf2f((unsigned short)(uu[j] >> 16));
    }
  }
  float invL = 1.0f / L;
  float* dst = out + ((size_t)(b * 2048 + qt * 32 + row)) * 128 + col0;
#pragma unroll
  for (int j = 0; j < 4; j++){
    float4 v = {acc[4 * j] * invL, acc[4 * j + 1] * invL,
                acc[4 * j + 2] * invL, acc[4 * j + 3] * invL};
    *reinterpret_cast<float4*>(dst + 4 * j) = v;
  }
}

extern "C" void kernel_launch(void* const* d_in, const int* in_sizes, int n_in,
                              void* d_out, int out_size, void* d_ws, size_t ws_size,
                              hipStream_t stream) {
  const float* x  = (const float*)d_in[0];
  const float* Wq = (const float*)d_in[1];
  const float* Wk = (const float*)d_in[2];
  const float* Wv = (const float*)d_in[3];
  float* out = (float*)d_out;

  char* ws = (char*)d_ws;
  unsigned short* Wtb = (unsigned short*)ws;                       // 786,432 B
  float* O            = (float*)(ws + 786432);                     // 25,165,824 B
  // attention partials OVERLAY the O buffer (O is dead after k_rope/k_vt)
  unsigned short* Opart = (unsigned short*)(ws + 786432);          // 16,777,216 B
  float* ml           = (float*)(ws + 786432 + 16777216);          //    524,288 B
  unsigned int* Qr    = (unsigned int*)(ws + 786432 + 25165824);   //  4,194,304 B
  unsigned int* Kr    = (unsigned int*)(ws + 786432 + 25165824 + 4194304);
  unsigned short* Vt  = (unsigned short*)(ws + 786432 + 25165824 + 2 * 4194304);

  hipLaunchKernelGGL(k_prepw, dim3(1536), dim3(256), 0, stream, Wq, Wk, Wv, Wtb);
  hipLaunchKernelGGL(k_gemm,  dim3(384),  dim3(256), 0, stream, x, Wtb, O);
  hipLaunchKernelGGL(k_rope,  dim3(4096), dim3(256), 0, stream, O, Qr, Kr);
  hipLaunchKernelGGL(k_vt,    dim3(256),  dim3(256), 0, stream, O, Vt);
  hipLaunchKernelGGL(k_attn_part, dim3(1280), dim3(128), 0, stream,
                     (const unsigned short*)Qr, (const unsigned short*)Kr, Vt, Opart, ml);
  hipLaunchKernelGGL(k_comb, dim3(512), dim3(256), 0, stream, Opart, ml, out);
}

// Round 3
// 94.662 us; speedup vs baseline: 2.8675x; 1.1701x over previous
//
#include <hip/hip_runtime.h>

typedef __bf16 bf16x8 __attribute__((ext_vector_type(8)));
typedef float f32x4 __attribute__((ext_vector_type(4)));

#define LOG2E 1.4426950408889634f

static __device__ __forceinline__ unsigned short f2bf(float f){
  unsigned int u = __builtin_bit_cast(unsigned int, f);
  u += 0x7FFFu + ((u >> 16) & 1u);
  return (unsigned short)(u >> 16);
}
static __device__ __forceinline__ float bf2f(unsigned short h){
  unsigned int u = ((unsigned int)h) << 16;
  return __builtin_bit_cast(float, u);
}

// ---------------- kernel 0: weights -> transposed bf16 [384][1024] ----------------
__global__ __launch_bounds__(256) void k_prepw(const float* __restrict__ Wq,
                                               const float* __restrict__ Wk,
                                               const float* __restrict__ Wv,
                                               unsigned short* __restrict__ Wtb){
  int idx = blockIdx.x * 256 + threadIdx.x;   // 0 .. 384*1024-1
  int m = idx >> 10;
  int k = idx & 1023;
  const float* W = (m < 128) ? Wq : ((m < 256) ? Wk : Wv);
  int n = m & 127;
  Wtb[idx] = f2bf(W[k * 128 + n]);
}

// ---------------- kernel 1: fused QKV projection + RoPE + V-transpose ----------------
// 64x128 tile, BK=64, 4 waves (2x2), 768 blocks. Epilogue: nblk 0/1 -> RoPE -> Qr/Kr,
// nblk 2 -> transpose -> Vt. All outputs bf16, coalesced via LDS re-layout.
__global__ __launch_bounds__(256) void k_qkv(const float* __restrict__ x,
                                             const unsigned short* __restrict__ Wtb,
                                             unsigned short* __restrict__ Qr,
                                             unsigned short* __restrict__ Kr,
                                             unsigned short* __restrict__ Vt){
  __shared__ __align__(16) unsigned short lds[64 * 72 + 128 * 72];  // 27648 B
  unsigned short* sA = lds;             // [64][72]
  unsigned short* sB = lds + 64 * 72;   // [128][72]

  // XCD-bijective swizzle: 768 = 8 * 96; triples sharing an x-panel stay on one XCD
  int bid0 = blockIdx.x;
  int wg = (bid0 & 7) * 96 + (bid0 >> 3);
  int mblk = wg / 3;
  int nblk = wg - mblk * 3;

  int tid = threadIdx.x;
  int lane = tid & 63, wid = tid >> 6;
  int wm = wid >> 1, wn = wid & 1;
  int g = lane >> 4, lr = lane & 15;

  f32x4 acc[2][4] = {};
  const float* xbase = x + (size_t)(mblk * 64) * 1024;
  const unsigned short* wbase = Wtb + (size_t)(nblk * 128) * 1024;

  for (int k0 = 0; k0 < 1024; k0 += 64){
    __syncthreads();
    // stage A: 64x64 fp32 -> bf16
#pragma unroll
    for (int p = 0; p < 4; p++){
      int idx = tid + p * 256;            // 0..1023
      int r = idx >> 4, c4 = (idx & 15) * 4;
      float4 v = *reinterpret_cast<const float4*>(xbase + (size_t)r * 1024 + k0 + c4);
      uint2 pk;
      pk.x = ((unsigned int)f2bf(v.y) << 16) | f2bf(v.x);
      pk.y = ((unsigned int)f2bf(v.w) << 16) | f2bf(v.z);
      *reinterpret_cast<uint2*>(&sA[r * 72 + c4]) = pk;
    }
    // stage B: 128x64 bf16
#pragma unroll
    for (int p = 0; p < 4; p++){
      int idx = tid + p * 256;            // 0..1023
      int r = idx >> 3, c8 = (idx & 7) * 8;
      *reinterpret_cast<uint4*>(&sB[r * 72 + c8]) =
        *reinterpret_cast<const uint4*>(wbase + (size_t)r * 1024 + k0 + c8);
    }
    __syncthreads();

#pragma unroll
    for (int ks = 0; ks < 2; ks++){
      bf16x8 af[2], bfr[4];
#pragma unroll
      for (int m = 0; m < 2; m++)
        af[m] = *reinterpret_cast<const bf16x8*>(&sA[(wm * 32 + m * 16 + lr) * 72 + ks * 32 + g * 8]);
#pragma unroll
      for (int n = 0; n < 4; n++)
        bfr[n] = *reinterpret_cast<const bf16x8*>(&sB[(wn * 64 + n * 16 + lr) * 72 + ks * 32 + g * 8]);
#pragma unroll
      for (int m = 0; m < 2; m++)
#pragma unroll
        for (int n = 0; n < 4; n++)
          acc[m][n] = __builtin_amdgcn_mfma_f32_16x16x32_bf16(af[m], bfr[n], acc[m][n], 0, 0, 0);
    }
  }
  __syncthreads();   // all MFMA LDS reads done; reuse LDS for epilogue

  int row0 = mblk * 64;                   // global row base (b*2048 + t)
  if (nblk < 2){
    // ---- RoPE epilogue -> Qr or Kr ----
    unsigned short* sE = lds;             // [64][136]
    float scale = nblk ? 1.0f : 0.08838834764831845f;  // 128^-0.5 folded into Q
#pragma unroll
    for (int n = 0; n < 4; n++){
      int col = wn * 64 + n * 16 + lr;
      int i = col >> 1;
      float theta = exp2f(13.287712379549449f * (2.0f - 2.0f * (float)i) * 0.015625f);
      float sgn = (lr & 1) ? -1.0f : 1.0f;
#pragma unroll
      for (int m = 0; m < 2; m++)
#pragma unroll
        for (int r = 0; r < 4; r++){
          int tl = wm * 32 + m * 16 + g * 4 + r;
          int t = (row0 + tl) & 2047;
          float s, c;
          sincosf((float)t * theta, &s, &c);
          float v = acc[m][n][r];
          float partner = __shfl_xor(v, 1);
          float res = (v * c + partner * sgn * s) * scale;
          sE[tl * 136 + col] = f2bf(res);
        }
    }
    __syncthreads();
    unsigned short* dst = (nblk ? Kr : Qr) + (size_t)row0 * 128;
#pragma unroll
    for (int p = 0; p < 4; p++){
      int u = tid + p * 256;              // 0..1023
      int tl = u >> 4, h0 = (u & 15) * 8;
      uint4 vv = *reinterpret_cast<const uint4*>(&sE[tl * 136 + h0]);
      *reinterpret_cast<uint4*>(dst + (size_t)tl * 128 + h0) = vv;
    }
  } else {
    // ---- V epilogue: transpose -> Vt[b][h][t] ----
    unsigned short* sE = lds;             // [128][72]
#pragma unroll
    for (int n = 0; n < 4; n++){
      int col = wn * 64 + n * 16 + lr;    // h
#pragma unroll
      for (int m = 0; m < 2; m++)
#pragma unroll
        for (int r = 0; r < 4; r++){
          int tl = wm * 32 + m * 16 + g * 4 + r;
          sE[col * 72 + tl] = f2bf(acc[m][n][r]);
        }
    }
    __syncthreads();
    int b = row0 >> 11;
    int t0 = row0 & 2047;
#pragma unroll
    for (int p = 0; p < 4; p++){
      int u = tid + p * 256;              // 0..1023
      int h = u >> 3, tc = (u & 7) * 8;
      uint4 vv = *reinterpret_cast<const uint4*>(&sE[h * 72 + tc]);
      *reinterpret_cast<uint4*>(Vt + ((size_t)(b * 128 + h)) * 2048 + t0 + tc) = vv;
    }
  }
}

// ---------------- kernel 4: causal flash attention, split-KV partials ----------------
__global__ __launch_bounds__(128) void k_attn_part(const unsigned short* __restrict__ Qr,
                                                   const unsigned short* __restrict__ Kr,
                                                   const unsigned short* __restrict__ Vt,
                                                   unsigned short* __restrict__ Opart,
                                                   float* __restrict__ ml){
  __shared__ __align__(16) unsigned short sK[32][136];   // [kv][h]
  __shared__ __align__(16) unsigned short sV[128][40];   // [h][kv]
  __shared__ __align__(16) unsigned short sP[2][16][40]; // per-wave [qrow][kv]

  int bid = blockIdx.x;
  int b = bid / 160;
  int rem = bid - b * 160;
  int qt, c;
  if (rem < 16)      { qt = rem;                    c = 0; }
  else if (rem < 48) { qt = 16 + ((rem - 16) >> 1); c = (rem - 16) & 1; }
  else if (rem < 96) { int r2 = rem - 48; int d = r2 / 3; qt = 32 + d; c = r2 - 3 * d; }
  else               { int r3 = rem - 96; qt = 48 + (r3 >> 2); c = r3 & 3; }

  int q_base = qt * 32;
  int kv_start = c * 512;
  int kv_end = min(kv_start + 512, q_base + 32);
  int niter = (kv_end - kv_start) >> 5;

  int tid = threadIdx.x, w = tid >> 6, lane = tid & 63;
  int g = lane >> 4, lr = lane & 15;

  int qrow = q_base + w * 16 + lr;
  const unsigned short* qptr = Qr + ((size_t)(b * 2048 + qrow)) * 128;
  bf16x8 qf[4];
#pragma unroll
  for (int hc = 0; hc < 4; hc++)
    qf[hc] = *reinterpret_cast<const bf16x8*>(qptr + hc * 32 + g * 8);

  f32x4 oacc[8] = {};
  float mrow[4], lrow[4];
#pragma unroll
  for (int r = 0; r < 4; r++){ mrow[r] = -1e30f; lrow[r] = 0.0f; }

  const unsigned short* Kb = Kr + (size_t)b * 2048 * 128;
  const unsigned short* Vb = Vt + (size_t)b * 128 * 2048;

  for (int it = 0; it < niter; it++){
    int kv0 = kv_start + it * 32;
    __syncthreads();
#pragma unroll
    for (int p = 0; p < 4; p++){
      int idx = tid + p * 128;               // 0..511
      int r = idx >> 4, c8 = (idx & 15) * 8;
      *reinterpret_cast<uint4*>(&sK[r][c8]) =
        *reinterpret_cast<const uint4*>(Kb + (size_t)(kv0 + r) * 128 + c8);
    }
#pragma unroll
    for (int p = 0; p < 4; p++){
      int idx = tid + p * 128;               // 0..511
      int h = idx >> 2, c8 = (idx & 3) * 8;
      *reinterpret_cast<uint4*>(&sV[h][c8]) =
        *reinterpret_cast<const uint4*>(Vb + (size_t)h * 2048 + kv0 + c8);
    }
    __syncthreads();

    f32x4 sacc[2] = {};
#pragma unroll
    for (int ct = 0; ct < 2; ct++){
      f32x4 a = {0.f, 0.f, 0.f, 0.f};
#pragma unroll
      for (int hc = 0; hc < 4; hc++){
        bf16x8 kf = *reinterpret_cast<const bf16x8*>(&sK[ct * 16 + lr][hc * 32 + g * 8]);
        a = __builtin_amdgcn_mfma_f32_16x16x32_bf16(qf[hc], kf, a, 0, 0, 0);
      }
      sacc[ct] = a;
    }

    float alpha[4];
#pragma unroll
    for (int r = 0; r < 4; r++){
      float s0 = sacc[0][r], s1 = sacc[1][r];
      int row = q_base + w * 16 + g * 4 + r;
      if (kv0 + lr      > row) s0 = -1e30f;
      if (kv0 + 16 + lr > row) s1 = -1e30f;
      float mx = fmaxf(s0, s1);
      mx = fmaxf(mx, __shfl_xor(mx, 1));
      mx = fmaxf(mx, __shfl_xor(mx, 2));
      mx = fmaxf(mx, __shfl_xor(mx, 4));
      mx = fmaxf(mx, __shfl_xor(mx, 8));
      float m = fmaxf(mrow[r], mx);
      float p0 = exp2f((s0 - m) * LOG2E);
      float p1 = exp2f((s1 - m) * LOG2E);
      float rs = p0 + p1;
      rs += __shfl_xor(rs, 1);
      rs += __shfl_xor(rs, 2);
      rs += __shfl_xor(rs, 4);
      rs += __shfl_xor(rs, 8);
      alpha[r] = exp2f((mrow[r] - m) * LOG2E);
      lrow[r] = lrow[r] * alpha[r] + rs;
      mrow[r] = m;
      sP[w][g * 4 + r][lr]      = f2bf(p0);
      sP[w][g * 4 + r][16 + lr] = f2bf(p1);
    }
#pragma unroll
    for (int ht = 0; ht < 8; ht++)
#pragma unroll
      for (int r = 0; r < 4; r++)
        oacc[ht][r] *= alpha[r];

    // sP written and read by the SAME wave -> no barrier needed
    bf16x8 pa = *reinterpret_cast<const bf16x8*>(&sP[w][lr][g * 8]);
#pragma unroll
    for (int ht = 0; ht < 8; ht++){
      bf16x8 vf = *reinterpret_cast<const bf16x8*>(&sV[ht * 16 + lr][g * 8]);
      oacc[ht] = __builtin_amdgcn_mfma_f32_16x16x32_bf16(pa, vf, oacc[ht], 0, 0, 0);
    }
  }

  size_t slot = (size_t)(b * 64 + qt) * 4 + c;
  unsigned short* op = Opart + slot * 4096;
  float* mlp = ml + slot * 64;
#pragma unroll
  for (int ht = 0; ht < 8; ht++)
#pragma unroll
    for (int r = 0; r < 4; r++){
      int rowl = w * 16 + g * 4 + r;
      op[rowl * 128 + ht * 16 + lr] = f2bf(oacc[ht][r]);
    }
  if (lr == 0){
#pragma unroll
    for (int r = 0; r < 4; r++){
      int rowl = w * 16 + g * 4 + r;
      mlp[rowl]      = mrow[r];
      mlp[32 + rowl] = lrow[r];
    }
  }
}

// ---------------- kernel 5: combine partials ----------------
__global__ __launch_bounds__(256) void k_comb(const unsigned short* __restrict__ Opart,
                                              const float* __restrict__ ml,
                                              float* __restrict__ out){
  int bid = blockIdx.x;          // 512 = 8 b * 64 qt
  int b = bid >> 6, qt = bid & 63;
  int nck = (qt >> 4) + 1;
  int tid = threadIdx.x;
  int row = tid >> 3;            // 0..31
  int col0 = (tid & 7) * 16;
  size_t slot0 = (size_t)(b * 64 + qt) * 4;

  float m_c[4], l_c[4];
  float M = -1e30f;
#pragma unroll
  for (int c = 0; c < 4; c++) if (c < nck){
    m_c[c] = ml[(slot0 + c) * 64 + row];
    l_c[c] = ml[(slot0 + c) * 64 + 32 + row];
    M = fmaxf(M, m_c[c]);
  }
  float L = 0.0f, wgt[4];
#pragma unroll
  for (int c = 0; c < 4; c++) if (c < nck){
    wgt[c] = exp2f((m_c[c] - M) * LOG2E);
    L += wgt[c] * l_c[c];
  }
  float acc[16] = {};
#pragma unroll
  for (int c = 0; c < 4; c++) if (c < nck){
    const unsigned short* src = Opart + (slot0 + c) * 4096 + row * 128 + col0;
    uint4 u0 = *reinterpret_cast<const uint4*>(src);
    uint4 u1 = *reinterpret_cast<const uint4*>(src + 8);
    unsigned int uu[8] = {u0.x, u0.y, u0.z, u0.w, u1.x, u1.y, u1.z, u1.w};
#pragma unroll
    for (int j = 0; j < 8; j++){
      acc[2 * j]     += wgt[c] * bf2f((unsigned short)(uu[j] & 0xFFFF));
      acc[2 * j + 1] += wgt[c] * bf2f((unsigned short)(uu[j] >> 16));
    }
  }
  float invL = 1.0f / L;
  float* dst = out + ((size_t)(b * 2048 + qt * 32 + row)) * 128 + col0;
#pragma unroll
  for (int j = 0; j < 4; j++){
    float4 v = {acc[4 * j] * invL, acc[4 * j + 1] * invL,
                acc[4 * j + 2] * invL, acc[4 * j + 3] * invL};
    *reinterpret_cast<float4*>(dst + 4 * j) = v;
  }
}

extern "C" void kernel_launch(void* const* d_in, const int* in_sizes, int n_in,
                              void* d_out, int out_size, void* d_ws, size_t ws_size,
                              hipStream_t stream) {
  const float* x  = (const float*)d_in[0];
  const float* Wq = (const float*)d_in[1];
  const float* Wk = (const float*)d_in[2];
  const float* Wv = (const float*)d_in[3];
  float* out = (float*)d_out;

  char* ws = (char*)d_ws;
  unsigned short* Wtb   = (unsigned short*)ws;                         //   786,432 B
  unsigned short* Qr    = (unsigned short*)(ws + 786432);              // 4,194,304 B
  unsigned short* Kr    = (unsigned short*)(ws + 786432 + 4194304);    // 4,194,304 B
  unsigned short* Vt    = (unsigned short*)(ws + 786432 + 2*4194304);  // 4,194,304 B
  unsigned short* Opart = (unsigned short*)(ws + 786432 + 3*4194304);  // 16,777,216 B
  float* ml             = (float*)(ws + 786432 + 3*4194304 + 16777216);//    524,288 B

  hipLaunchKernelGGL(k_prepw, dim3(1536), dim3(256), 0, stream, Wq, Wk, Wv, Wtb);
  hipLaunchKernelGGL(k_qkv,   dim3(768),  dim3(256), 0, stream, x, Wtb, Qr, Kr, Vt);
  hipLaunchKernelGGL(k_attn_part, dim3(1280), dim3(128), 0, stream, Qr, Kr, Vt, Opart, ml);
  hipLaunchKernelGGL(k_comb, dim3(512), dim3(256), 0, stream, Opart, ml, out);
}